// Round 5
// baseline (357.034 us; speedup 1.0000x reference)
//
#include <hip/hip_runtime.h>
#include <hip/hip_bf16.h>
#include <math.h>

#define B_   4
#define S_   4096
#define D_   1024
#define M_   (B_*S_)        // 16384 rows
#define NCAT (4*D_)         // 4096 concat projection cols
#define KD   1024

#define NCHUNK 128          // scan chunks along S
#define CHLEN  (S_/NCHUNK)  // 32

typedef __bf16 bf16x8 __attribute__((ext_vector_type(8)));
typedef float  f32x4  __attribute__((ext_vector_type(4)));
typedef ushort ushort8v __attribute__((ext_vector_type(8)));

__device__ __forceinline__ ushort f2bf(float f) {
  union { float f; uint u; } v; v.f = f;
  uint u = v.u;
  return (ushort)((u + 0x7FFFu + ((u >> 16) & 1u)) >> 16);  // RNE
}
__device__ __forceinline__ float bf2f(uint bits16) {
  union { uint u; float f; } v; v.u = bits16 << 16;
  return v.f;
}

// global -> LDS direct (16B per lane). LDS dest linear: wave-uniform base + lane*16.
#define GLL(g, l) __builtin_amdgcn_global_load_lds( \
  (const __attribute__((address_space(1))) uint32_t*)(uintptr_t)(g), \
  (__attribute__((address_space(3))) uint32_t*)(uint32_t)(uintptr_t)(l), 16, 0, 0)

#define MFMA_(a, b, c) __builtin_amdgcn_mfma_f32_16x16x32_bf16(a, b, c, 0, 0, 0)

// ---------------- K0: conversions ----------------
__global__ void k_cvt_f2b4(const float* __restrict__ in, ushort* __restrict__ out, int n4) {
  int i = blockIdx.x * blockDim.x + threadIdx.x;
  if (i >= n4) return;
  const float4 v = ((const float4*)in)[i];
  uint2 o;
  o.x = (uint)f2bf(v.x) | ((uint)f2bf(v.y) << 16);
  o.y = (uint)f2bf(v.z) | ((uint)f2bf(v.w) << 16);
  ((uint2*)out)[i] = o;
}

// Interleaved Wcat: row n -> proj p=(n>>4)&3 of channel e=(n>>6)*16+(n&15)
__global__ void k_build_wcat(const float* __restrict__ wdel, const float* __restrict__ wsel,
                             const float* __restrict__ win,  const float* __restrict__ wgat,
                             ushort* __restrict__ wcat) {
  int i = blockIdx.x * blockDim.x + threadIdx.x;  // one per 4 elements
  int E = i * 4;
  int n   = E >> 10;
  int col = E & 1023;
  int p = (n >> 4) & 3;
  int e = ((n >> 6) << 4) + (n & 15);
  const float* src = (p == 0) ? wdel : (p == 1) ? wsel : (p == 2) ? win : wgat;
  const float4 v = *(const float4*)&src[(size_t)e * 1024 + col];
  uint2 o;
  o.x = (uint)f2bf(v.x) | ((uint)f2bf(v.y) << 16);
  o.y = (uint)f2bf(v.z) | ((uint)f2bf(v.w) << 16);
  *(uint2*)&wcat[E] = o;
}

__global__ void k_abase(const float* __restrict__ log_a, float* __restrict__ abase) {
  int i = blockIdx.x * blockDim.x + threadIdx.x;
  if (i < D_) abase[i] = 1.f / (1.f + __expf(-log_a[i]));
}

// -------- 256x256 GEMM, K-tile 64, 8-phase m201-style schedule, vmcnt(6) --------
// C[m][n] = sum_k A[m][k]*B[n][k].
// LDS per buf (ushort): A: kk*8192 + la_row*32 + s*8 ; B: +16384, lb_row.
// Row perms make phase-regions contiguous (128 LDS rows each):
//   la_row(g) = (g&63) | ((g&64)<<1) | ((g&128)>>1)   (involution)
//   lb_row(g) = (g&31) | ((g&0xC0)>>1) | ((g&32)<<2)
// Swizzle (verified zero-conflict): chunk c of row r stored at slot s = c ^ ((r>>1)&3)
// (perms preserve row bits 1..2, so the swizzle math is unchanged).
// Regions: A0 = la 0-127 (mf0-3), A1 = la 128-255 (mf4-7); B0 = lb 0-127 (nf0-1), B1 (nf2-3).
// Phase reads: ph1{A0,B0}=12, ph2{A1}=8, ph3{B1}=4, ph4{}=0 (registers reused);
// each region is LDS-read in exactly ONE phase -> tile T+2 staged into freed regions.
template<int MODE>
__global__ __launch_bounds__(512, 2) void gemm9(
    const ushort* __restrict__ Ab, const ushort* __restrict__ Bb, int nbn,
    float* __restrict__ outf,
    ushort* __restrict__ dec, ushort* __restrict__ uu, ushort* __restrict__ gat,
    const float* __restrict__ abase)
{
  __shared__ ushort lds[65536];  // 128 KB: 2 bufs x (A 32KB + B 32KB)

  const int nwg = gridDim.x;
  const int bid = blockIdx.x;
  const int nb  = (bid & 7) * (nwg >> 3) + (bid >> 3);   // XCD-bijective (nwg%8==0)
  const int brow = nb / nbn, bcol = nb % nbn;
  const int t = threadIdx.x, lane = t & 63, w = t >> 6;
  const int wm = w >> 2, wn = w & 3;
  const int l15 = lane & 15, lhi = lane >> 4;

  // ---- staging: thread t covers (lr = t>>2, slot cs = t&3) of a region, both kk
  const int lr = t >> 2, cs = t & 3;
  const int csw = cs ^ ((lr >> 1) & 3);                  // data chunk held in slot cs
  const int gA0 = (lr & 63) | ((lr & 64) << 1);          // inverse row perms
  const int gA1 = gA0 | 64;
  const int gB0 = (lr & 31) | ((lr & 0x60) << 1);
  const int gB1 = gB0 | 32;
  const ushort* aR0 = Ab + (size_t)(brow * 256 + gA0) * KD + csw * 8;
  const ushort* aR1 = Ab + (size_t)(brow * 256 + gA1) * KD + csw * 8;
  const ushort* bR0 = Bb + (size_t)(bcol * 256 + gB0) * KD + csw * 8;
  const ushort* bR1 = Bb + (size_t)(bcol * 256 + gB1) * KD + csw * 8;
  const int dstT = t * 8;                                // lr*32 + cs*8

// stage one 16KB region (2 GLL/thread: kk0,kk1) of tile at k-offset KO
#define STG(PB, OPOFF, SRC, R, KO) do { \
    GLL((SRC) + (KO),      &lds[(PB) + (OPOFF) + (R) * 4096 + dstT]); \
    GLL((SRC) + (KO) + 32, &lds[(PB) + (OPOFF) + 8192 + (R) * 4096 + dstT]); } while (0)

  // ---- fragment read bases (swizzled)
  const int swp = (lhi ^ ((l15 >> 1) & 3)) * 8;
  const ushort* fA  = &lds[(wm * 64 + l15) * 32 + swp];           // + kk*8192 + (mf>>2)*4096 + (mf&3)*512
  const ushort* fB  = &lds[16384 + (wn * 32 + l15) * 32 + swp];   // + kk*8192 + (nf>>1)*4096 + (nf&1)*512
  const ushort* fA1 = fA + 32768;
  const ushort* fB1 = fB + 32768;

#define RD_A(DST, FP, HOFF) \
    _Pragma("unroll") for (int m = 0; m < 4; ++m) \
    _Pragma("unroll") for (int kk = 0; kk < 2; ++kk) \
      DST[m][kk] = *(const bf16x8*)&(FP)[kk * 8192 + (HOFF) + m * 512];
#define RD_B(DST, FP, HOFF) \
    _Pragma("unroll") for (int n = 0; n < 2; ++n) \
    _Pragma("unroll") for (int kk = 0; kk < 2; ++kk) \
      DST[n][kk] = *(const bf16x8*)&(FP)[kk * 8192 + (HOFF) + n * 512];
#define MM4(AR, BV, M0, N0) \
    _Pragma("unroll") for (int m = 0; m < 4; ++m) \
    _Pragma("unroll") for (int n = 0; n < 2; ++n) \
    _Pragma("unroll") for (int kk = 0; kk < 2; ++kk) \
      acc[(M0) + m][(N0) + n] = MFMA_(AR[m][kk], BV[n][kk], acc[(M0) + m][(N0) + n]);
#define BAR   __builtin_amdgcn_s_barrier()
#define PRIO1 __builtin_amdgcn_s_setprio(1)
#define PRIO0 __builtin_amdgcn_s_setprio(0)
#define WAITV6 asm volatile("s_waitcnt vmcnt(6)" ::: "memory")

  f32x4 acc[8][4] = {};
  bf16x8 a03[4][2], a47[4][2], b01[2][2], b23[2][2];

  // prologue: buf0 <- tile0 (A0,A1,B0,B1), buf1 <- tile1 (A0,A1,B0); b1.B1 staged at ph1
  STG(0, 0, aR0, 0, 0);
  STG(0, 0, aR1, 1, 0);
  STG(0, 16384, bR0, 0, 0);
  STG(0, 16384, bR1, 1, 0);
  STG(32768, 0, aR0, 0, 64);
  STG(32768, 0, aR1, 1, 64);
  STG(32768, 16384, bR0, 0, 64);

  for (int i = 0; i < 8; ++i) {
    const int ko1 = (2 * i + 1) * 64;
    const int t2 = 2 * i + 2, t3 = 2 * i + 3;
    const int ko2 = (t2 < 16 ? t2 : 15) * 64;   // tail: dead re-stage (uniform vmcnt)
    const int ko3 = (t3 < 16 ? t3 : 15) * 64;
    // ---- ph1: read buf0 A0+B0; stage b1.B1 <- 2i+1
    WAITV6; BAR;
    RD_A(a03, fA, 0) RD_B(b01, fB, 0)
    STG(32768, 16384, bR1, 1, ko1);
    BAR; PRIO1; MM4(a03, b01, 0, 0) PRIO0; BAR;
    // ---- ph2: read buf0 A1; stage b0.A0 <- 2i+2
    RD_A(a47, fA, 4096)
    STG(0, 0, aR0, 0, ko2);
    BAR; PRIO1; MM4(a47, b01, 4, 0) PRIO0; BAR;
    // ---- ph3: read buf0 B1; stage b0.A1
    RD_B(b23, fB, 4096)
    STG(0, 0, aR1, 1, ko2);
    BAR; PRIO1; MM4(a47, b23, 4, 2) PRIO0; BAR;
    // ---- ph4: no reads; stage b0.B0
    STG(0, 16384, bR0, 0, ko2);
    BAR; PRIO1; MM4(a03, b23, 0, 2) PRIO0; BAR;
    // ---- ph5: read buf1 A0+B0; stage b0.B1
    WAITV6; BAR;
    RD_A(a03, fA1, 0) RD_B(b01, fB1, 0)
    STG(0, 16384, bR1, 1, ko2);
    BAR; PRIO1; MM4(a03, b01, 0, 0) PRIO0; BAR;
    // ---- ph6: read buf1 A1; stage b1.A0 <- 2i+3
    RD_A(a47, fA1, 4096)
    STG(32768, 0, aR0, 0, ko3);
    BAR; PRIO1; MM4(a47, b01, 4, 0) PRIO0; BAR;
    // ---- ph7: read buf1 B1; stage b1.A1
    RD_B(b23, fB1, 4096)
    STG(32768, 0, aR1, 1, ko3);
    BAR; PRIO1; MM4(a47, b23, 4, 2) PRIO0; BAR;
    // ---- ph8: no reads; stage b1.B0
    STG(32768, 16384, bR0, 0, ko3);
    BAR; PRIO1; MM4(a03, b23, 0, 2) PRIO0; BAR;
  }

  asm volatile("s_waitcnt vmcnt(0)" ::: "memory");
  __syncthreads();

  // ---- epilogue ----
  const int rowb = wm * 128;
  if constexpr (MODE == 0) {
    // reuse LDS as [256][64] bf16 x3 (dec/u/gate), XOR-swizzled 8-ushort chunks
    ushort* ldsD = lds;
    ushort* ldsU = lds + 16384;
    ushort* ldsG = lds + 32768;
    const int chl = wn * 16 + l15;           // channel within block's 64
    const int chg = bcol * 64 + chl;         // global channel
    const float ab = abase[chg];
#pragma unroll
    for (int mf = 0; mf < 8; ++mf) {
      const int rl0 = rowb + mf * 16 + lhi * 4;
#pragma unroll
      for (int r = 0; r < 4; ++r) {
        const float zd = acc[mf][0][r];
        const float zs = acc[mf][1][r];
        const float zi = acc[mf][2][r];
        const float zg = acc[mf][3][r];
        float sp = fmaxf(zd, 0.f) + log1pf(__expf(-fabsf(zd)));
        sp = fmaxf(sp, 1e-4f);
        const float dv = __expf(-sp * ab);
        const float sv = 1.f / (1.f + __expf(-zs));
        float tt = __expf(-2.f * fabsf(zi));
        float tv = (1.f - tt) / (1.f + tt);
        tv = (zi < 0.f) ? -tv : tv;
        const float gv = 1.f / (1.f + __expf(-zg));
        const int row = rl0 + r;
        const int idx = row * 64 + ((((chl >> 3) ^ (row & 7)) << 3) | (chl & 7));
        ldsD[idx] = f2bf(dv);
        ldsU[idx] = f2bf(sv * tv);
        ldsG[idx] = f2bf(gv);
      }
    }
    __syncthreads();
    const int srow = t >> 3, cD = t & 7;
    const size_t gbase = (size_t)(brow * 256) * D_ + bcol * 64 + cD * 8;
#pragma unroll
    for (int itp = 0; itp < 4; ++itp) {
      const int row = itp * 64 + srow;
      const int lidx = row * 64 + ((cD ^ (row & 7)) << 3);
      const size_t g = gbase + (size_t)row * D_;
      *(ushort8v*)&dec[g] = *(const ushort8v*)&ldsD[lidx];
      *(ushort8v*)&uu[g]  = *(const ushort8v*)&ldsU[lidx];
      *(ushort8v*)&gat[g] = *(const ushort8v*)&ldsG[lidx];
    }
  } else {
    const int colb = bcol * 256 + wn * 64;
#pragma unroll
    for (int mf = 0; mf < 8; ++mf) {
      const int rl0 = brow * 256 + rowb + mf * 16 + lhi * 4;
#pragma unroll
      for (int nf = 0; nf < 4; ++nf) {
        const int gc = colb + nf * 16 + l15;
#pragma unroll
        for (int r = 0; r < 4; ++r)
          outf[(size_t)(rl0 + r) * 1024 + gc] = acc[mf][nf][r];
      }
    }
  }
#undef STG
#undef RD_A
#undef RD_B
#undef MM4
}

// ---------------- scan (3-phase chunked, exact affine composition) ----------------
__global__ __launch_bounds__(512) void k_scanA(
    const ushort* __restrict__ dec, const ushort* __restrict__ uu,
    float* __restrict__ cP, float* __restrict__ cL)
{
  const int t  = threadIdx.x;
  const int c  = blockIdx.x & (NCHUNK - 1);
  const int b  = blockIdx.x >> 7;
  const int e2 = t * 2;
  size_t base = ((size_t)b * S_ + (size_t)c * CHLEN) * D_ + e2;
  float P0 = 1.f, P1 = 1.f, L0 = 0.f, L1 = 0.f;
  for (int i = 0; i < CHLEN; ++i) {
    const uint dv = *(const uint*)(dec + base);
    const uint uv = *(const uint*)(uu + base);
    float d0 = bf2f(dv & 0xffffu), d1 = bf2f(dv >> 16);
    P0 *= d0; L0 = fmaf(d0, L0, bf2f(uv & 0xffffu));
    P1 *= d1; L1 = fmaf(d1, L1, bf2f(uv >> 16));
    base += D_;
  }
  size_t o = ((size_t)b * NCHUNK + c) * D_ + e2;
  cP[o] = P0; cP[o + 1] = P1; cL[o] = L0; cL[o + 1] = L1;
}

__global__ __launch_bounds__(64) void k_scanB(
    const float* __restrict__ cP, const float* __restrict__ cL, float* __restrict__ carry)
{
  const int idx = blockIdx.x * 64 + threadIdx.x;  // 0..B_*D_-1
  const int b = idx >> 10, e = idx & 1023;
  float st = 0.f;
  size_t base = (size_t)b * NCHUNK * D_ + e;
  for (int c = 0; c < NCHUNK; ++c) {
    size_t o = base + (size_t)c * D_;
    carry[o] = st;
    st = fmaf(cP[o], st, cL[o]);
  }
}

__global__ __launch_bounds__(512) void k_scanC(
    const ushort* __restrict__ dec, const ushort* __restrict__ uu,
    const ushort* __restrict__ gat, const float* __restrict__ carry,
    ushort* __restrict__ outb)
{
  const int t  = threadIdx.x;
  const int c  = blockIdx.x & (NCHUNK - 1);
  const int b  = blockIdx.x >> 7;
  const int e2 = t * 2;
  size_t co = ((size_t)b * NCHUNK + c) * D_ + e2;
  float s0 = carry[co], s1 = carry[co + 1];
  size_t base = ((size_t)b * S_ + (size_t)c * CHLEN) * D_ + e2;
  for (int i = 0; i < CHLEN; ++i) {
    const uint dv = *(const uint*)(dec + base);
    const uint uv = *(const uint*)(uu + base);
    const uint gv = *(const uint*)(gat + base);
    s0 = fmaf(bf2f(dv & 0xffffu), s0, bf2f(uv & 0xffffu));
    s1 = fmaf(bf2f(dv >> 16),     s1, bf2f(uv >> 16));
    float o0 = bf2f(gv & 0xffffu) * s0;
    float o1 = bf2f(gv >> 16)     * s1;
    *(uint*)(outb + base) = (uint)f2bf(o0) | ((uint)f2bf(o1) << 16);
    base += D_;
  }
}

// ---------------- launcher ----------------
extern "C" void kernel_launch(void* const* d_in, const int* in_sizes, int n_in,
                              void* d_out, int out_size, void* d_ws, size_t ws_size,
                              hipStream_t stream) {
  const float* x     = (const float*)d_in[0];
  const float* W_in  = (const float*)d_in[1];
  const float* W_sel = (const float*)d_in[2];
  const float* W_gat = (const float*)d_in[3];
  const float* W_out = (const float*)d_in[4];
  const float* W_del = (const float*)d_in[5];
  const float* log_a = (const float*)d_in[6];
  float* y = (float*)d_out;

  char* ws = (char*)d_ws;
  size_t off = 0;
  auto alloc = [&](size_t bytes) { char* p = ws + off; off += (bytes + 255) & ~(size_t)255; return p; };
  ushort* xbf   = (ushort*)alloc((size_t)M_ * D_ * 2);   // reused as outb after GEMM0
  ushort* wcat  = (ushort*)alloc((size_t)NCAT * D_ * 2);
  ushort* woutb = (ushort*)alloc((size_t)D_ * D_ * 2);
  ushort* dec   = (ushort*)alloc((size_t)M_ * D_ * 2);
  ushort* uu    = (ushort*)alloc((size_t)M_ * D_ * 2);
  ushort* gat   = (ushort*)alloc((size_t)M_ * D_ * 2);
  float*  cP    = (float*)alloc((size_t)B_ * NCHUNK * D_ * 4);
  float*  cL    = (float*)alloc((size_t)B_ * NCHUNK * D_ * 4);
  float*  carry = (float*)alloc((size_t)B_ * NCHUNK * D_ * 4);
  float*  abase = (float*)alloc(D_ * 4);
  ushort* outb  = xbf;

  // K0: conversions
  k_cvt_f2b4<<<(M_ * D_ / 4 + 255) / 256, 256, 0, stream>>>(x, xbf, M_ * D_ / 4);
  k_build_wcat<<<(NCAT * D_ / 4 + 255) / 256, 256, 0, stream>>>(W_del, W_sel, W_in, W_gat, wcat);
  k_cvt_f2b4<<<(D_ * D_ / 4 + 255) / 256, 256, 0, stream>>>(W_out, woutb, D_ * D_ / 4);
  k_abase<<<(D_ + 255) / 256, 256, 0, stream>>>(log_a, abase);

  // K1: fused 4-projection GEMM + activation epilogue (interleaved Wcat)
  gemm9<0><<<(M_ / 256) * (NCAT / 256), 512, 0, stream>>>(
      xbf, wcat, NCAT / 256, nullptr, dec, uu, gat, abase);

  // K2: chunked scan
  k_scanA<<<B_ * NCHUNK, 512, 0, stream>>>(dec, uu, cP, cL);
  k_scanB<<<(B_ * D_) / 64, 64, 0, stream>>>(cP, cL, carry);
  k_scanC<<<B_ * NCHUNK, 512, 0, stream>>>(dec, uu, gat, carry, outb);

  // K3: output GEMM -> fp32 y
  gemm9<1><<<(M_ / 256) * (D_ / 256), 512, 0, stream>>>(
      outb, woutb, D_ / 256, y, nullptr, nullptr, nullptr, nullptr);
}

// Round 6
// 324.478 us; speedup vs baseline: 1.1003x; 1.1003x over previous
//
#include <hip/hip_runtime.h>
#include <hip/hip_bf16.h>
#include <math.h>

#define B_   4
#define S_   4096
#define D_   1024
#define M_   (B_*S_)        // 16384 rows
#define NCAT (4*D_)         // 4096 concat projection cols
#define KD   1024

#define NCHUNK 128          // scan chunks along S
#define CHLEN  (S_/NCHUNK)  // 32

typedef __bf16 bf16x8 __attribute__((ext_vector_type(8)));
typedef float  f32x4  __attribute__((ext_vector_type(4)));
typedef ushort ushort8v __attribute__((ext_vector_type(8)));

__device__ __forceinline__ ushort f2bf(float f) {
  union { float f; uint u; } v; v.f = f;
  uint u = v.u;
  return (ushort)((u + 0x7FFFu + ((u >> 16) & 1u)) >> 16);  // RNE
}
__device__ __forceinline__ float bf2f(uint bits16) {
  union { uint u; float f; } v; v.u = bits16 << 16;
  return v.f;
}

// global -> LDS direct (16B per lane). LDS dest linear: wave-uniform base + lane*16.
#define GLL(g, l) __builtin_amdgcn_global_load_lds( \
  (const __attribute__((address_space(1))) uint32_t*)(uintptr_t)(g), \
  (__attribute__((address_space(3))) uint32_t*)(uint32_t)(uintptr_t)(l), 16, 0, 0)

#define MFMA_(a, b, c) __builtin_amdgcn_mfma_f32_16x16x32_bf16(a, b, c, 0, 0, 0)

// ---------------- K0: conversions ----------------
__global__ void k_cvt_f2b4(const float* __restrict__ in, ushort* __restrict__ out, int n4) {
  int i = blockIdx.x * blockDim.x + threadIdx.x;
  if (i >= n4) return;
  const float4 v = ((const float4*)in)[i];
  uint2 o;
  o.x = (uint)f2bf(v.x) | ((uint)f2bf(v.y) << 16);
  o.y = (uint)f2bf(v.z) | ((uint)f2bf(v.w) << 16);
  ((uint2*)out)[i] = o;
}

// Interleaved Wcat: row n -> proj p=(n>>4)&3 of channel e=(n>>6)*16+(n&15)
__global__ void k_build_wcat(const float* __restrict__ wdel, const float* __restrict__ wsel,
                             const float* __restrict__ win,  const float* __restrict__ wgat,
                             ushort* __restrict__ wcat) {
  int i = blockIdx.x * blockDim.x + threadIdx.x;  // one per 4 elements
  int E = i * 4;
  int n   = E >> 10;
  int col = E & 1023;
  int p = (n >> 4) & 3;
  int e = ((n >> 6) << 4) + (n & 15);
  const float* src = (p == 0) ? wdel : (p == 1) ? wsel : (p == 2) ? win : wgat;
  const float4 v = *(const float4*)&src[(size_t)e * 1024 + col];
  uint2 o;
  o.x = (uint)f2bf(v.x) | ((uint)f2bf(v.y) << 16);
  o.y = (uint)f2bf(v.z) | ((uint)f2bf(v.w) << 16);
  *(uint2*)&wcat[E] = o;
}

__global__ void k_abase(const float* __restrict__ log_a, float* __restrict__ abase) {
  int i = blockIdx.x * blockDim.x + threadIdx.x;
  if (i < D_) abase[i] = 1.f / (1.f + __expf(-log_a[i]));
}

// -------- 256x256 GEMM, K-tile 64, 4-phase deep pipeline, one vmcnt(8)/tile --------
// C[m][n] = sum_k A[m][k]*B[n][k].
// LDS per buf (ushort): A: kk*8192 + la_row*32 + s*8 ; B: +16384, lb_row.
// Row perms make regions contiguous (128 LDS rows each) and preserve row bits 1-2
// (so the zero-conflict swizzle s = c ^ ((r>>1)&3) is unchanged):
//   la_row(g) = (g&63) | ((g&128)>>1) | ((g&64)<<1)
//   lb_row(g) = (g&31) | ((g&0xC0)>>1) | ((g&32)<<2)
// Regions: A0 = la 0-127 (mf0-3), A1 = la 128-255 (mf4-7); B0 = lb 0-127 (nf0-1), B1 (nf2-3).
// Phase order picked so <=64 fragment VGPRs are live (R5 spilled at 96):
//   ph1: rd a03,b01  MFMA a03*b01          (A0,B0 freed)
//   ph2: rd b23      MFMA a03*b23  stg A0  (B1, then a03 dies)
//   ph3: rd a47      MFMA a47*b23  stg B0  (A1, b23 dies)
//   ph4:             MFMA a47*b01  stg B1,A1 ; vmcnt(8)
// Every region staged >=1 barrier-phase after its last LDS read; one wait/tile;
// stage->consume distance ~7 phases (>> HBM latency).
template<int MODE>
__global__ __launch_bounds__(512, 2) void gemm9(
    const ushort* __restrict__ Ab, const ushort* __restrict__ Bb, int nbn,
    float* __restrict__ outf,
    ushort* __restrict__ dec, ushort* __restrict__ uu, ushort* __restrict__ gat,
    const float* __restrict__ abase)
{
  __shared__ ushort lds[65536];  // 128 KB: 2 bufs x (A 32KB + B 32KB)

  const int nwg = gridDim.x;
  const int bid = blockIdx.x;
  const int nb  = (bid & 7) * (nwg >> 3) + (bid >> 3);   // XCD-bijective (nwg%8==0)
  const int brow = nb / nbn, bcol = nb % nbn;
  const int t = threadIdx.x, lane = t & 63, w = t >> 6;
  const int wm = w >> 2, wn = w & 3;
  const int l15 = lane & 15, lhi = lane >> 4;

  // ---- staging: thread t covers (lr = t>>2, slot cs = t&3) of a region, both kk
  const int lr = t >> 2, cs = t & 3;
  const int csw = cs ^ ((lr >> 1) & 3);                  // data chunk held in slot cs
  const int gA0 = (lr & 63) | ((lr & 64) << 1);          // inverse row perms
  const int gA1 = gA0 | 64;
  const int gB0 = (lr & 31) | ((lr & 0x60) << 1);
  const int gB1 = gB0 | 32;
  const ushort* aR0 = Ab + (size_t)(brow * 256 + gA0) * KD + csw * 8;
  const ushort* aR1 = Ab + (size_t)(brow * 256 + gA1) * KD + csw * 8;
  const ushort* bR0 = Bb + (size_t)(bcol * 256 + gB0) * KD + csw * 8;
  const ushort* bR1 = Bb + (size_t)(bcol * 256 + gB1) * KD + csw * 8;
  const int dstT = t * 8;                                // lr*32 + cs*8

// stage one 16KB region (2 GLL/thread: kk0,kk1) of tile at k-offset KO
#define STG(PB, OPOFF, SRC, R, KO) do { \
    GLL((SRC) + (KO),      &lds[(PB) + (OPOFF) + (R) * 4096 + dstT]); \
    GLL((SRC) + (KO) + 32, &lds[(PB) + (OPOFF) + 8192 + (R) * 4096 + dstT]); } while (0)

  // ---- fragment read bases (swizzled)
  const int swp = (lhi ^ ((l15 >> 1) & 3)) * 8;
  const ushort* fA  = &lds[(wm * 64 + l15) * 32 + swp];           // + kk*8192 + (mf>>2)*4096 + (mf&3)*512
  const ushort* fB  = &lds[16384 + (wn * 32 + l15) * 32 + swp];   // + kk*8192 + (nf>>1)*4096 + (nf&1)*512
  const ushort* fA1 = fA + 32768;
  const ushort* fB1 = fB + 32768;

#define RD_A(DST, FP, HOFF) \
    _Pragma("unroll") for (int m = 0; m < 4; ++m) \
    _Pragma("unroll") for (int kk = 0; kk < 2; ++kk) \
      DST[m][kk] = *(const bf16x8*)&(FP)[kk * 8192 + (HOFF) + m * 512];
#define RD_B(DST, FP, HOFF) \
    _Pragma("unroll") for (int n = 0; n < 2; ++n) \
    _Pragma("unroll") for (int kk = 0; kk < 2; ++kk) \
      DST[n][kk] = *(const bf16x8*)&(FP)[kk * 8192 + (HOFF) + n * 512];
#define MM4(AR, BV, M0, N0) \
    _Pragma("unroll") for (int m = 0; m < 4; ++m) \
    _Pragma("unroll") for (int n = 0; n < 2; ++n) \
    _Pragma("unroll") for (int kk = 0; kk < 2; ++kk) \
      acc[(M0) + m][(N0) + n] = MFMA_(AR[m][kk], BV[n][kk], acc[(M0) + m][(N0) + n]);
#define BAR   __builtin_amdgcn_s_barrier()
#define PRIO1 __builtin_amdgcn_s_setprio(1)
#define PRIO0 __builtin_amdgcn_s_setprio(0)

  f32x4 acc[8][4] = {};

// one K-tile: reads buf at byte-base PB (0 or 32768); stages tile at k-offset KO
// into the same buf's regions as they free. Entered with tile data guaranteed
// (vmcnt(8)+barrier at the END of the previous tile / prologue).
#define KTILE(PB, FAx, FBx, KO) do { \
    bf16x8 a03[4][2], a47[4][2], b01[2][2], b23[2][2]; \
    RD_A(a03, FAx, 0) RD_B(b01, FBx, 0) \
    BAR; PRIO1; MM4(a03, b01, 0, 0) PRIO0; BAR; \
    RD_B(b23, FBx, 4096) \
    STG(PB, 0, aR0, 0, KO); \
    BAR; PRIO1; MM4(a03, b23, 0, 2) PRIO0; BAR; \
    RD_A(a47, FAx, 4096) \
    STG(PB, 16384, bR0, 0, KO); \
    BAR; PRIO1; MM4(a47, b23, 4, 2) PRIO0; BAR; \
    STG(PB, 16384, bR1, 1, KO); \
    STG(PB, 0, aR1, 1, KO); \
    BAR; PRIO1; MM4(a47, b01, 4, 0) PRIO0; \
    asm volatile("s_waitcnt vmcnt(8)" ::: "memory"); \
    BAR; \
  } while (0)

  // prologue: stage tile0 -> buf0, tile1 -> buf1 (4 STG = 8 GLL each)
  STG(0, 0, aR0, 0, 0);
  STG(0, 16384, bR0, 0, 0);
  STG(0, 16384, bR1, 1, 0);
  STG(0, 0, aR1, 1, 0);
  STG(32768, 0, aR0, 0, 64);
  STG(32768, 16384, bR0, 0, 64);
  STG(32768, 16384, bR1, 1, 64);
  STG(32768, 0, aR1, 1, 64);
  asm volatile("s_waitcnt vmcnt(8)" ::: "memory");
  BAR;

  for (int i = 0; i < 8; ++i) {
    const int t2 = 2 * i + 2, t3 = 2 * i + 3;
    const int ko2 = (t2 < 16 ? t2 : 15) * 64;   // tail: dead re-stage (uniform vmcnt)
    const int ko3 = (t3 < 16 ? t3 : 15) * 64;
    KTILE(0, fA, fB, ko2);
    KTILE(32768, fA1, fB1, ko3);
  }

  asm volatile("s_waitcnt vmcnt(0)" ::: "memory");
  __syncthreads();

  // ---- epilogue ----
  const int rowb = wm * 128;
  if constexpr (MODE == 0) {
    // reuse LDS as [256][64] bf16 x3 (dec/u/gate), XOR-swizzled 8-ushort chunks
    ushort* ldsD = lds;
    ushort* ldsU = lds + 16384;
    ushort* ldsG = lds + 32768;
    const int chl = wn * 16 + l15;           // channel within block's 64
    const int chg = bcol * 64 + chl;         // global channel
    const float ab = abase[chg];
#pragma unroll
    for (int mf = 0; mf < 8; ++mf) {
      const int rl0 = rowb + mf * 16 + lhi * 4;
#pragma unroll
      for (int r = 0; r < 4; ++r) {
        const float zd = acc[mf][0][r];
        const float zs = acc[mf][1][r];
        const float zi = acc[mf][2][r];
        const float zg = acc[mf][3][r];
        float sp = fmaxf(zd, 0.f) + log1pf(__expf(-fabsf(zd)));
        sp = fmaxf(sp, 1e-4f);
        const float dv = __expf(-sp * ab);
        const float sv = 1.f / (1.f + __expf(-zs));
        float tt = __expf(-2.f * fabsf(zi));
        float tv = (1.f - tt) / (1.f + tt);
        tv = (zi < 0.f) ? -tv : tv;
        const float gv = 1.f / (1.f + __expf(-zg));
        const int row = rl0 + r;
        const int idx = row * 64 + ((((chl >> 3) ^ (row & 7)) << 3) | (chl & 7));
        ldsD[idx] = f2bf(dv);
        ldsU[idx] = f2bf(sv * tv);
        ldsG[idx] = f2bf(gv);
      }
    }
    __syncthreads();
    const int srow = t >> 3, cD = t & 7;
    const size_t gbase = (size_t)(brow * 256) * D_ + bcol * 64 + cD * 8;
#pragma unroll
    for (int itp = 0; itp < 4; ++itp) {
      const int row = itp * 64 + srow;
      const int lidx = row * 64 + ((cD ^ (row & 7)) << 3);
      const size_t g = gbase + (size_t)row * D_;
      *(ushort8v*)&dec[g] = *(const ushort8v*)&ldsD[lidx];
      *(ushort8v*)&uu[g]  = *(const ushort8v*)&ldsU[lidx];
      *(ushort8v*)&gat[g] = *(const ushort8v*)&ldsG[lidx];
    }
  } else {
    const int colb = bcol * 256 + wn * 64;
#pragma unroll
    for (int mf = 0; mf < 8; ++mf) {
      const int rl0 = brow * 256 + rowb + mf * 16 + lhi * 4;
#pragma unroll
      for (int nf = 0; nf < 4; ++nf) {
        const int gc = colb + nf * 16 + l15;
#pragma unroll
        for (int r = 0; r < 4; ++r)
          outf[(size_t)(rl0 + r) * 1024 + gc] = acc[mf][nf][r];
      }
    }
  }
#undef KTILE
#undef STG
#undef RD_A
#undef RD_B
#undef MM4
}

// ---------------- scan (3-phase chunked, exact affine composition) ----------------
__global__ __launch_bounds__(512) void k_scanA(
    const ushort* __restrict__ dec, const ushort* __restrict__ uu,
    float* __restrict__ cP, float* __restrict__ cL)
{
  const int t  = threadIdx.x;
  const int c  = blockIdx.x & (NCHUNK - 1);
  const int b  = blockIdx.x >> 7;
  const int e2 = t * 2;
  size_t base = ((size_t)b * S_ + (size_t)c * CHLEN) * D_ + e2;
  float P0 = 1.f, P1 = 1.f, L0 = 0.f, L1 = 0.f;
  for (int i = 0; i < CHLEN; ++i) {
    const uint dv = *(const uint*)(dec + base);
    const uint uv = *(const uint*)(uu + base);
    float d0 = bf2f(dv & 0xffffu), d1 = bf2f(dv >> 16);
    P0 *= d0; L0 = fmaf(d0, L0, bf2f(uv & 0xffffu));
    P1 *= d1; L1 = fmaf(d1, L1, bf2f(uv >> 16));
    base += D_;
  }
  size_t o = ((size_t)b * NCHUNK + c) * D_ + e2;
  cP[o] = P0; cP[o + 1] = P1; cL[o] = L0; cL[o + 1] = L1;
}

__global__ __launch_bounds__(64) void k_scanB(
    const float* __restrict__ cP, const float* __restrict__ cL, float* __restrict__ carry)
{
  const int idx = blockIdx.x * 64 + threadIdx.x;  // 0..B_*D_-1
  const int b = idx >> 10, e = idx & 1023;
  float st = 0.f;
  size_t base = (size_t)b * NCHUNK * D_ + e;
  for (int c = 0; c < NCHUNK; ++c) {
    size_t o = base + (size_t)c * D_;
    carry[o] = st;
    st = fmaf(cP[o], st, cL[o]);
  }
}

__global__ __launch_bounds__(512) void k_scanC(
    const ushort* __restrict__ dec, const ushort* __restrict__ uu,
    const ushort* __restrict__ gat, const float* __restrict__ carry,
    ushort* __restrict__ outb)
{
  const int t  = threadIdx.x;
  const int c  = blockIdx.x & (NCHUNK - 1);
  const int b  = blockIdx.x >> 7;
  const int e2 = t * 2;
  size_t co = ((size_t)b * NCHUNK + c) * D_ + e2;
  float s0 = carry[co], s1 = carry[co + 1];
  size_t base = ((size_t)b * S_ + (size_t)c * CHLEN) * D_ + e2;
  for (int i = 0; i < CHLEN; ++i) {
    const uint dv = *(const uint*)(dec + base);
    const uint uv = *(const uint*)(uu + base);
    const uint gv = *(const uint*)(gat + base);
    s0 = fmaf(bf2f(dv & 0xffffu), s0, bf2f(uv & 0xffffu));
    s1 = fmaf(bf2f(dv >> 16),     s1, bf2f(uv >> 16));
    float o0 = bf2f(gv & 0xffffu) * s0;
    float o1 = bf2f(gv >> 16)     * s1;
    *(uint*)(outb + base) = (uint)f2bf(o0) | ((uint)f2bf(o1) << 16);
    base += D_;
  }
}

// ---------------- launcher ----------------
extern "C" void kernel_launch(void* const* d_in, const int* in_sizes, int n_in,
                              void* d_out, int out_size, void* d_ws, size_t ws_size,
                              hipStream_t stream) {
  const float* x     = (const float*)d_in[0];
  const float* W_in  = (const float*)d_in[1];
  const float* W_sel = (const float*)d_in[2];
  const float* W_gat = (const float*)d_in[3];
  const float* W_out = (const float*)d_in[4];
  const float* W_del = (const float*)d_in[5];
  const float* log_a = (const float*)d_in[6];
  float* y = (float*)d_out;

  char* ws = (char*)d_ws;
  size_t off = 0;
  auto alloc = [&](size_t bytes) { char* p = ws + off; off += (bytes + 255) & ~(size_t)255; return p; };
  ushort* xbf   = (ushort*)alloc((size_t)M_ * D_ * 2);   // reused as outb after GEMM0
  ushort* wcat  = (ushort*)alloc((size_t)NCAT * D_ * 2);
  ushort* woutb = (ushort*)alloc((size_t)D_ * D_ * 2);
  ushort* dec   = (ushort*)alloc((size_t)M_ * D_ * 2);
  ushort* uu    = (ushort*)alloc((size_t)M_ * D_ * 2);
  ushort* gat   = (ushort*)alloc((size_t)M_ * D_ * 2);
  float*  cP    = (float*)alloc((size_t)B_ * NCHUNK * D_ * 4);
  float*  cL    = (float*)alloc((size_t)B_ * NCHUNK * D_ * 4);
  float*  carry = (float*)alloc((size_t)B_ * NCHUNK * D_ * 4);
  float*  abase = (float*)alloc(D_ * 4);
  ushort* outb  = xbf;

  // K0: conversions
  k_cvt_f2b4<<<(M_ * D_ / 4 + 255) / 256, 256, 0, stream>>>(x, xbf, M_ * D_ / 4);
  k_build_wcat<<<(NCAT * D_ / 4 + 255) / 256, 256, 0, stream>>>(W_del, W_sel, W_in, W_gat, wcat);
  k_cvt_f2b4<<<(D_ * D_ / 4 + 255) / 256, 256, 0, stream>>>(W_out, woutb, D_ * D_ / 4);
  k_abase<<<(D_ + 255) / 256, 256, 0, stream>>>(log_a, abase);

  // K1: fused 4-projection GEMM + activation epilogue (interleaved Wcat)
  gemm9<0><<<(M_ / 256) * (NCAT / 256), 512, 0, stream>>>(
      xbf, wcat, NCAT / 256, nullptr, dec, uu, gat, abase);

  // K2: chunked scan
  k_scanA<<<B_ * NCHUNK, 512, 0, stream>>>(dec, uu, cP, cL);
  k_scanB<<<(B_ * D_) / 64, 64, 0, stream>>>(cP, cL, carry);
  k_scanC<<<B_ * NCHUNK, 512, 0, stream>>>(dec, uu, gat, carry, outb);

  // K3: output GEMM -> fp32 y
  gemm9<1><<<(M_ / 256) * (D_ / 256), 512, 0, stream>>>(
      outb, woutb, D_ / 256, y, nullptr, nullptr, nullptr, nullptr);
}

// Round 8
// 320.756 us; speedup vs baseline: 1.1131x; 1.0116x over previous
//
#include <hip/hip_runtime.h>
#include <hip/hip_bf16.h>
#include <math.h>

#define B_   4
#define S_   4096
#define D_   1024
#define M_   (B_*S_)        // 16384 rows
#define NCAT (4*D_)         // 4096 concat projection cols
#define KD   1024

#define NCHUNK 128          // scan chunks along S
#define CHLEN  (S_/NCHUNK)  // 32

typedef __bf16 bf16x8 __attribute__((ext_vector_type(8)));
typedef float  f32x4  __attribute__((ext_vector_type(4)));
typedef ushort ushort8v __attribute__((ext_vector_type(8)));

__device__ __forceinline__ ushort sbf(float f) {           // f32 -> bf16 (RNE, hw cvt)
  return __builtin_bit_cast(ushort, (__bf16)f);
}
__device__ __forceinline__ uint pk2bf(float lo, float hi) {
  return (uint)sbf(lo) | ((uint)sbf(hi) << 16);
}
__device__ __forceinline__ float bf2f(uint bits16) {
  union { uint u; float f; } v; v.u = bits16 << 16;
  return v.f;
}

// global -> LDS direct (16B per lane). LDS dest linear: wave-uniform base + lane*16.
#define GLL(g, l) __builtin_amdgcn_global_load_lds( \
  (const __attribute__((address_space(1))) uint32_t*)(uintptr_t)(g), \
  (__attribute__((address_space(3))) uint32_t*)(uint32_t)(uintptr_t)(l), 16, 0, 0)

#define MFMA_(a, b, c) __builtin_amdgcn_mfma_f32_16x16x32_bf16(a, b, c, 0, 0, 0)

// ---------------- K0: conversions ----------------
__global__ void k_cvt_f2b4(const float* __restrict__ in, ushort* __restrict__ out, int n4) {
  int i = blockIdx.x * blockDim.x + threadIdx.x;
  if (i >= n4) return;
  const float4 v = ((const float4*)in)[i];
  uint2 o;
  o.x = pk2bf(v.x, v.y);
  o.y = pk2bf(v.z, v.w);
  ((uint2*)out)[i] = o;
}

// Interleaved Wcat: row n -> proj p=(n>>4)&3 of channel e=(n>>6)*16+(n&15)
__global__ void k_build_wcat(const float* __restrict__ wdel, const float* __restrict__ wsel,
                             const float* __restrict__ win,  const float* __restrict__ wgat,
                             ushort* __restrict__ wcat) {
  int i = blockIdx.x * blockDim.x + threadIdx.x;  // one per 4 elements
  int E = i * 4;
  int n   = E >> 10;
  int col = E & 1023;
  int p = (n >> 4) & 3;
  int e = ((n >> 6) << 4) + (n & 15);
  const float* src = (p == 0) ? wdel : (p == 1) ? wsel : (p == 2) ? win : wgat;
  const float4 v = *(const float4*)&src[(size_t)e * 1024 + col];
  uint2 o;
  o.x = pk2bf(v.x, v.y);
  o.y = pk2bf(v.z, v.w);
  *(uint2*)&wcat[E] = o;
}

__global__ void k_abase(const float* __restrict__ log_a, float* __restrict__ abase) {
  int i = blockIdx.x * blockDim.x + threadIdx.x;
  if (i < D_) abase[i] = 1.f / (1.f + __expf(-log_a[i]));
}

// -------- 256x256 GEMM, K-tile 64, 4-phase deep pipeline, one vmcnt(8)/tile --------
// R6 schedule; addressing in reduced-VGPR form (u32 voffset + uniform base; buf1 via
// +32768 ushort imm). ALL LDS offsets in USHORT units (R7's byte/ushort mix = NaN bug):
//   buf PB in {0, 32768}; A region at PB+0, B region at PB+16384;
//   region idx = kk*8192 + R*4096 + lr*32 + s*8.
template<int MODE>
__global__ __launch_bounds__(512, 2) void gemm9(
    const ushort* __restrict__ Ab, const ushort* __restrict__ Bb, int nbn,
    float* __restrict__ outf,
    ushort* __restrict__ dec, ushort* __restrict__ uu, ushort* __restrict__ gat,
    const float* __restrict__ abase)
{
  __shared__ ushort lds[65536];  // 128 KB: 2 bufs x (A 32KB + B 32KB)

  const int nwg = gridDim.x;
  const int bid = blockIdx.x;
  const int nb  = (bid & 7) * (nwg >> 3) + (bid >> 3);   // XCD-bijective (nwg%8==0)
  const int brow = nb / nbn, bcol = nb % nbn;
  const int t = threadIdx.x, lane = t & 63, w = t >> 6;
  const int wm = w >> 2, wn = w & 3;
  const int l15 = lane & 15, lhi = lane >> 4;

  // ---- staging: thread t covers (lr = t>>2, slot cs = t&3) of a region, both kk
  const int lr = t >> 2, cs = t & 3;
  const int csw = cs ^ ((lr >> 1) & 3);                  // data chunk held in slot cs
  const int gA0 = (lr & 63) | ((lr & 64) << 1);          // inverse row perms
  const int gA1 = gA0 | 64;
  const int gB0 = (lr & 31) | ((lr & 0x60) << 1);
  const int gB1 = gB0 | 32;
  // u32 BYTE offsets from the matrix bases (saddr form; saves 64-bit ptr regs)
  const uint vA0 = ((uint)(brow * 256 + gA0) * KD + (uint)csw * 8) * 2u;
  const uint vA1 = ((uint)(brow * 256 + gA1) * KD + (uint)csw * 8) * 2u;
  const uint vB0 = ((uint)(bcol * 256 + gB0) * KD + (uint)csw * 8) * 2u;
  const uint vB1 = ((uint)(bcol * 256 + gB1) * KD + (uint)csw * 8) * 2u;
  const char* Ab8 = (const char*)Ab;
  const char* Bb8 = (const char*)Bb;
  const int dstT = t * 8;                                // lr*32 + cs*8 (ushort idx)

// stage one 16KB region (2 GLL/thread: kk0, kk1 = +64B global) of tile at k-offset
// KO (elements). PB/OPOFF/dest all USHORT indices.
#define STG(PB, OPOFF, SRC8, VOFF, R, KO) do { \
    GLL((SRC8) + (VOFF) + (KO) * 2,      &lds[(PB) + (OPOFF) + (R) * 4096 + dstT]); \
    GLL((SRC8) + (VOFF) + (KO) * 2 + 64, &lds[(PB) + (OPOFF) + 8192 + (R) * 4096 + dstT]); } while (0)

  // ---- fragment read bases (swizzled); buf1 via +32768 ushort imm
  const int swp = (lhi ^ ((l15 >> 1) & 3)) * 8;
  const ushort* fA  = &lds[(wm * 64 + l15) * 32 + swp];           // + PB + kk*8192 + (mf>>2)*4096 + (mf&3)*512
  const ushort* fB  = &lds[16384 + (wn * 32 + l15) * 32 + swp];   // + PB + kk*8192 + (nf>>1)*4096 + (nf&1)*512

#define RD_A(DST, PB, HOFF) \
    _Pragma("unroll") for (int m = 0; m < 4; ++m) \
    _Pragma("unroll") for (int kk = 0; kk < 2; ++kk) \
      DST[m][kk] = *(const bf16x8*)&fA[(PB) + kk * 8192 + (HOFF) + m * 512];
#define RD_B(DST, PB, HOFF) \
    _Pragma("unroll") for (int n = 0; n < 2; ++n) \
    _Pragma("unroll") for (int kk = 0; kk < 2; ++kk) \
      DST[n][kk] = *(const bf16x8*)&fB[(PB) + kk * 8192 + (HOFF) + n * 512];
#define MM4(AR, BV, M0, N0) \
    _Pragma("unroll") for (int m = 0; m < 4; ++m) \
    _Pragma("unroll") for (int n = 0; n < 2; ++n) \
    _Pragma("unroll") for (int kk = 0; kk < 2; ++kk) \
      acc[(M0) + m][(N0) + n] = MFMA_(AR[m][kk], BV[n][kk], acc[(M0) + m][(N0) + n]);
#define BAR   __builtin_amdgcn_s_barrier()
#define PRIO1 __builtin_amdgcn_s_setprio(1)
#define PRIO0 __builtin_amdgcn_s_setprio(0)

  f32x4 acc[8][4] = {};

// one K-tile: reads buf at ushort-base PB (0 or 32768); stages tile at k-offset KO
// into the same buf's regions as they free (region staged >= 1 barrier after its
// last read). Entered with tile data guaranteed (vmcnt(8)+barrier at prev tile end).
#define KTILE(PB, KO) do { \
    bf16x8 a03[4][2], a47[4][2], b01[2][2], b23[2][2]; \
    RD_A(a03, PB, 0) RD_B(b01, PB, 0) \
    BAR; PRIO1; MM4(a03, b01, 0, 0) PRIO0; BAR; \
    RD_B(b23, PB, 4096) \
    STG(PB, 0, Ab8, vA0, 0, KO); \
    BAR; PRIO1; MM4(a03, b23, 0, 2) PRIO0; BAR; \
    RD_A(a47, PB, 4096) \
    STG(PB, 16384, Bb8, vB0, 0, KO); \
    BAR; PRIO1; MM4(a47, b23, 4, 2) PRIO0; BAR; \
    STG(PB, 16384, Bb8, vB1, 1, KO); \
    STG(PB, 0, Ab8, vA1, 1, KO); \
    BAR; PRIO1; MM4(a47, b01, 4, 0) PRIO0; \
    asm volatile("s_waitcnt vmcnt(8)" ::: "memory"); \
    BAR; \
  } while (0)

  // prologue: stage tile0 -> buf0, tile1 -> buf1 (4 STG = 8 GLL each)
  STG(0, 0, Ab8, vA0, 0, 0);
  STG(0, 16384, Bb8, vB0, 0, 0);
  STG(0, 16384, Bb8, vB1, 1, 0);
  STG(0, 0, Ab8, vA1, 1, 0);
  STG(32768, 0, Ab8, vA0, 0, 64);
  STG(32768, 16384, Bb8, vB0, 0, 64);
  STG(32768, 16384, Bb8, vB1, 1, 64);
  STG(32768, 0, Ab8, vA1, 1, 64);
  asm volatile("s_waitcnt vmcnt(8)" ::: "memory");
  BAR;

#pragma unroll 1
  for (int i = 0; i < 8; ++i) {
    const int t2 = 2 * i + 2, t3 = 2 * i + 3;
    const int ko2 = (t2 < 16 ? t2 : 15) * 64;   // tail: dead re-stage (uniform vmcnt)
    const int ko3 = (t3 < 16 ? t3 : 15) * 64;
    KTILE(0, ko2);
    KTILE(32768, ko3);
  }

  asm volatile("s_waitcnt vmcnt(0)" ::: "memory");
  __syncthreads();

  // ---- epilogue ----
  const int rowb = wm * 128;
  if constexpr (MODE == 0) {
    // reuse LDS as [256][64] bf16 x3 (dec/u/gate), XOR-swizzled 8-ushort chunks
    ushort* ldsD = lds;
    ushort* ldsU = lds + 16384;
    ushort* ldsG = lds + 32768;
    const int chl = wn * 16 + l15;           // channel within block's 64
    const int chg = bcol * 64 + chl;         // global channel
    const float ab = abase[chg];
#pragma unroll
    for (int mf = 0; mf < 8; ++mf) {
      const int rl0 = rowb + mf * 16 + lhi * 4;
#pragma unroll
      for (int r = 0; r < 4; ++r) {
        const float zd = acc[mf][0][r];
        const float zs = acc[mf][1][r];
        const float zi = acc[mf][2][r];
        const float zg = acc[mf][3][r];
        float sp = fmaxf(zd, 0.f) + log1pf(__expf(-fabsf(zd)));
        sp = fmaxf(sp, 1e-4f);
        const float dv = __expf(-sp * ab);
        const float sv = 1.f / (1.f + __expf(-zs));
        float tt = __expf(-2.f * fabsf(zi));
        float tv = (1.f - tt) / (1.f + tt);
        tv = (zi < 0.f) ? -tv : tv;
        const float gv = 1.f / (1.f + __expf(-zg));
        const int row = rl0 + r;
        const int idx = row * 64 + ((((chl >> 3) ^ (row & 7)) << 3) | (chl & 7));
        ldsD[idx] = sbf(dv);
        ldsU[idx] = sbf(sv * tv);
        ldsG[idx] = sbf(gv);
      }
    }
    __syncthreads();
    const int srow = t >> 3, cD = t & 7;
    const size_t gbase = (size_t)(brow * 256) * D_ + bcol * 64 + cD * 8;
#pragma unroll
    for (int itp = 0; itp < 4; ++itp) {
      const int row = itp * 64 + srow;
      const int lidx = row * 64 + ((cD ^ (row & 7)) << 3);
      const size_t g = gbase + (size_t)row * D_;
      *(ushort8v*)&dec[g] = *(const ushort8v*)&ldsD[lidx];
      *(ushort8v*)&uu[g]  = *(const ushort8v*)&ldsU[lidx];
      *(ushort8v*)&gat[g] = *(const ushort8v*)&ldsG[lidx];
    }
  } else {
    const int colb = bcol * 256 + wn * 64;
#pragma unroll
    for (int mf = 0; mf < 8; ++mf) {
      const int rl0 = brow * 256 + rowb + mf * 16 + lhi * 4;
#pragma unroll
      for (int nf = 0; nf < 4; ++nf) {
        const int gc = colb + nf * 16 + l15;
#pragma unroll
        for (int r = 0; r < 4; ++r)
          outf[(size_t)(rl0 + r) * 1024 + gc] = acc[mf][nf][r];
      }
    }
  }
#undef KTILE
#undef STG
#undef RD_A
#undef RD_B
#undef MM4
}

// ---------------- scan (3-phase chunked, exact affine composition) ----------------
__global__ __launch_bounds__(512) void k_scanA(
    const ushort* __restrict__ dec, const ushort* __restrict__ uu,
    float* __restrict__ cP, float* __restrict__ cL)
{
  const int t  = threadIdx.x;
  const int c  = blockIdx.x & (NCHUNK - 1);
  const int b  = blockIdx.x >> 7;
  const int e2 = t * 2;
  size_t base = ((size_t)b * S_ + (size_t)c * CHLEN) * D_ + e2;
  float P0 = 1.f, P1 = 1.f, L0 = 0.f, L1 = 0.f;
  for (int i = 0; i < CHLEN; ++i) {
    const uint dv = *(const uint*)(dec + base);
    const uint uv = *(const uint*)(uu + base);
    float d0 = bf2f(dv & 0xffffu), d1 = bf2f(dv >> 16);
    P0 *= d0; L0 = fmaf(d0, L0, bf2f(uv & 0xffffu));
    P1 *= d1; L1 = fmaf(d1, L1, bf2f(uv >> 16));
    base += D_;
  }
  size_t o = ((size_t)b * NCHUNK + c) * D_ + e2;
  cP[o] = P0; cP[o + 1] = P1; cL[o] = L0; cL[o + 1] = L1;
}

__global__ __launch_bounds__(64) void k_scanB(
    const float* __restrict__ cP, const float* __restrict__ cL, float* __restrict__ carry)
{
  const int idx = blockIdx.x * 64 + threadIdx.x;  // 0..B_*D_-1
  const int b = idx >> 10, e = idx & 1023;
  float st = 0.f;
  size_t base = (size_t)b * NCHUNK * D_ + e;
  for (int c = 0; c < NCHUNK; ++c) {
    size_t o = base + (size_t)c * D_;
    carry[o] = st;
    st = fmaf(cP[o], st, cL[o]);
  }
}

__global__ __launch_bounds__(512) void k_scanC(
    const ushort* __restrict__ dec, const ushort* __restrict__ uu,
    const ushort* __restrict__ gat, const float* __restrict__ carry,
    ushort* __restrict__ outb)
{
  const int t  = threadIdx.x;
  const int c  = blockIdx.x & (NCHUNK - 1);
  const int b  = blockIdx.x >> 7;
  const int e2 = t * 2;
  size_t co = ((size_t)b * NCHUNK + c) * D_ + e2;
  float s0 = carry[co], s1 = carry[co + 1];
  size_t base = ((size_t)b * S_ + (size_t)c * CHLEN) * D_ + e2;
  for (int i = 0; i < CHLEN; ++i) {
    const uint dv = *(const uint*)(dec + base);
    const uint uv = *(const uint*)(uu + base);
    const uint gv = *(const uint*)(gat + base);
    s0 = fmaf(bf2f(dv & 0xffffu), s0, bf2f(uv & 0xffffu));
    s1 = fmaf(bf2f(dv >> 16),     s1, bf2f(uv >> 16));
    float o0 = bf2f(gv & 0xffffu) * s0;
    float o1 = bf2f(gv >> 16)     * s1;
    *(uint*)(outb + base) = pk2bf(o0, o1);
    base += D_;
  }
}

// ---------------- launcher ----------------
extern "C" void kernel_launch(void* const* d_in, const int* in_sizes, int n_in,
                              void* d_out, int out_size, void* d_ws, size_t ws_size,
                              hipStream_t stream) {
  const float* x     = (const float*)d_in[0];
  const float* W_in  = (const float*)d_in[1];
  const float* W_sel = (const float*)d_in[2];
  const float* W_gat = (const float*)d_in[3];
  const float* W_out = (const float*)d_in[4];
  const float* W_del = (const float*)d_in[5];
  const float* log_a = (const float*)d_in[6];
  float* y = (float*)d_out;

  char* ws = (char*)d_ws;
  size_t off = 0;
  auto alloc = [&](size_t bytes) { char* p = ws + off; off += (bytes + 255) & ~(size_t)255; return p; };
  ushort* xbf   = (ushort*)alloc((size_t)M_ * D_ * 2);   // reused as outb after GEMM0
  ushort* wcat  = (ushort*)alloc((size_t)NCAT * D_ * 2);
  ushort* woutb = (ushort*)alloc((size_t)D_ * D_ * 2);
  ushort* dec   = (ushort*)alloc((size_t)M_ * D_ * 2);
  ushort* uu    = (ushort*)alloc((size_t)M_ * D_ * 2);
  ushort* gat   = (ushort*)alloc((size_t)M_ * D_ * 2);
  float*  cP    = (float*)alloc((size_t)B_ * NCHUNK * D_ * 4);
  float*  cL    = (float*)alloc((size_t)B_ * NCHUNK * D_ * 4);
  float*  carry = (float*)alloc((size_t)B_ * NCHUNK * D_ * 4);
  float*  abase = (float*)alloc(D_ * 4);
  ushort* outb  = xbf;

  // K0: conversions
  k_cvt_f2b4<<<(M_ * D_ / 4 + 255) / 256, 256, 0, stream>>>(x, xbf, M_ * D_ / 4);
  k_build_wcat<<<(NCAT * D_ / 4 + 255) / 256, 256, 0, stream>>>(W_del, W_sel, W_in, W_gat, wcat);
  k_cvt_f2b4<<<(D_ * D_ / 4 + 255) / 256, 256, 0, stream>>>(W_out, woutb, D_ * D_ / 4);
  k_abase<<<(D_ + 255) / 256, 256, 0, stream>>>(log_a, abase);

  // K1: fused 4-projection GEMM + activation epilogue (interleaved Wcat)
  gemm9<0><<<(M_ / 256) * (NCAT / 256), 512, 0, stream>>>(
      xbf, wcat, NCAT / 256, nullptr, dec, uu, gat, abase);

  // K2: chunked scan
  k_scanA<<<B_ * NCHUNK, 512, 0, stream>>>(dec, uu, cP, cL);
  k_scanB<<<(B_ * D_) / 64, 64, 0, stream>>>(cP, cL, carry);
  k_scanC<<<B_ * NCHUNK, 512, 0, stream>>>(dec, uu, gat, carry, outb);

  // K3: output GEMM -> fp32 y
  gemm9<1><<<(M_ / 256) * (D_ / 256), 512, 0, stream>>>(
      outb, woutb, D_ / 256, y, nullptr, nullptr, nullptr, nullptr);
}

// Round 9
// 313.120 us; speedup vs baseline: 1.1402x; 1.0244x over previous
//
#include <hip/hip_runtime.h>
#include <hip/hip_bf16.h>
#include <math.h>

#define B_   4
#define S_   4096
#define D_   1024
#define M_   (B_*S_)        // 16384 rows
#define NCAT (4*D_)         // 4096 concat projection cols
#define KD   1024

#define NCHUNK 128          // scan chunks along S
#define CHLEN  (S_/NCHUNK)  // 32

typedef __bf16 bf16x8 __attribute__((ext_vector_type(8)));
typedef float  f32x4  __attribute__((ext_vector_type(4)));
typedef ushort ushort8v __attribute__((ext_vector_type(8)));

__device__ __forceinline__ ushort sbf(float f) {           // f32 -> bf16 (RNE, hw cvt)
  return __builtin_bit_cast(ushort, (__bf16)f);
}
__device__ __forceinline__ uint pk2bf(float lo, float hi) {
  return (uint)sbf(lo) | ((uint)sbf(hi) << 16);
}
__device__ __forceinline__ float bf2f(uint bits16) {
  union { uint u; float f; } v; v.u = bits16 << 16;
  return v.f;
}

// global -> LDS direct (16B per lane). LDS dest linear: wave-uniform base + lane*16.
#define GLL(g, l) __builtin_amdgcn_global_load_lds( \
  (const __attribute__((address_space(1))) uint32_t*)(uintptr_t)(g), \
  (__attribute__((address_space(3))) uint32_t*)(uint32_t)(uintptr_t)(l), 16, 0, 0)

#define MFMA_(a, b, c) __builtin_amdgcn_mfma_f32_16x16x32_bf16(a, b, c, 0, 0, 0)

// ---------------- K0: conversions ----------------
__global__ void k_cvt_f2b4(const float* __restrict__ in, ushort* __restrict__ out, int n4) {
  int i = blockIdx.x * blockDim.x + threadIdx.x;
  if (i >= n4) return;
  const float4 v = ((const float4*)in)[i];
  uint2 o;
  o.x = pk2bf(v.x, v.y);
  o.y = pk2bf(v.z, v.w);
  ((uint2*)out)[i] = o;
}

// Interleaved Wcat: row n -> proj p=(n>>4)&3 of channel e=(n>>6)*16+(n&15)
__global__ void k_build_wcat(const float* __restrict__ wdel, const float* __restrict__ wsel,
                             const float* __restrict__ win,  const float* __restrict__ wgat,
                             ushort* __restrict__ wcat) {
  int i = blockIdx.x * blockDim.x + threadIdx.x;  // one per 4 elements
  int E = i * 4;
  int n   = E >> 10;
  int col = E & 1023;
  int p = (n >> 4) & 3;
  int e = ((n >> 6) << 4) + (n & 15);
  const float* src = (p == 0) ? wdel : (p == 1) ? wsel : (p == 2) ? win : wgat;
  const float4 v = *(const float4*)&src[(size_t)e * 1024 + col];
  uint2 o;
  o.x = pk2bf(v.x, v.y);
  o.y = pk2bf(v.z, v.w);
  *(uint2*)&wcat[E] = o;
}

__global__ void k_abase(const float* __restrict__ log_a, float* __restrict__ abase) {
  int i = blockIdx.x * blockDim.x + threadIdx.x;
  if (i < D_) abase[i] = 1.f / (1.f + __expf(-log_a[i]));
}

// -------- 256x256 GEMM, K-tile 64, ONE barrier/phase, ds_read prefetched 1 phase ----
// C[m][n] = sum_k A[m][k]*B[n][k].  Layout identical to R8 (verified):
//   buf PB in {0, 32768} ushorts; A region at PB+0, B at PB+16384;
//   idx = kk*8192 + R*4096 + lr*32 + s*8; swizzle s = c ^ ((r>>1)&3) (0-conflict).
// Per tile, 4 phases, each = [RDs for NEXT quadrant | STG freed region | MFMA | BAR]:
//   ph1: RD A0kk1,B1      MFMA(a03,b01)           (a03kk0,b01 prefetched prev ph4)
//   ph2: RD A1kk0  STG B0 MFMA(a03,b23)
//   ph3: RD A1kk1  STG A0,B1 MFMA(a47,b23) vmcnt(6)
//   ph4: RD nextbuf A0kk0,B0  STG A1  MFMA(a47,b01)
// WAR: every STG >=1 barrier after the phase whose lgkm-wait completed that region's
// reads. vmcnt(6) at ph3 = prev tile's 8 GLLs landed -> ph4 cross-buf prefetch safe.
// b01 double-buffered (BU=use, BN=load) since ph4 uses and loads it.
template<int MODE>
__global__ __launch_bounds__(512, 2) void gemm10(
    const ushort* __restrict__ Ab, const ushort* __restrict__ Bb, int nbn,
    float* __restrict__ outf,
    ushort* __restrict__ dec, ushort* __restrict__ uu, ushort* __restrict__ gat,
    const float* __restrict__ abase)
{
  __shared__ ushort lds[65536];  // 128 KB: 2 bufs x (A 32KB + B 32KB)

  const int nwg = gridDim.x;
  const int bid = blockIdx.x;
  const int nb  = (bid & 7) * (nwg >> 3) + (bid >> 3);   // XCD-bijective (nwg%8==0)
  const int brow = nb / nbn, bcol = nb % nbn;
  const int t = threadIdx.x, lane = t & 63, w = t >> 6;
  const int wm = w >> 2, wn = w & 3;
  const int l15 = lane & 15, lhi = lane >> 4;

  // ---- staging: thread t covers (lr = t>>2, slot cs = t&3) of a region, both kk
  const int lr = t >> 2, cs = t & 3;
  const int csw = cs ^ ((lr >> 1) & 3);                  // data chunk held in slot cs
  const int gA0 = (lr & 63) | ((lr & 64) << 1);          // inverse row perms
  const int gA1 = gA0 | 64;
  const int gB0 = (lr & 31) | ((lr & 0x60) << 1);
  const int gB1 = gB0 | 32;
  // u32 BYTE offsets from the matrix bases (saddr form)
  const uint vA0 = ((uint)(brow * 256 + gA0) * KD + (uint)csw * 8) * 2u;
  const uint vA1 = ((uint)(brow * 256 + gA1) * KD + (uint)csw * 8) * 2u;
  const uint vB0 = ((uint)(bcol * 256 + gB0) * KD + (uint)csw * 8) * 2u;
  const uint vB1 = ((uint)(bcol * 256 + gB1) * KD + (uint)csw * 8) * 2u;
  const char* Ab8 = (const char*)Ab;
  const char* Bb8 = (const char*)Bb;
  const int dstT = t * 8;                                // lr*32 + cs*8 (ushort idx)

// stage one 16KB region (2 GLL: kk0, kk1 = +64B global) at k-offset KO (elements)
#define STG(PB, OPOFF, SRC8, VOFF, R, KO) do { \
    GLL((SRC8) + (VOFF) + (KO) * 2,      &lds[(PB) + (OPOFF) + (R) * 4096 + dstT]); \
    GLL((SRC8) + (VOFF) + (KO) * 2 + 64, &lds[(PB) + (OPOFF) + 8192 + (R) * 4096 + dstT]); } while (0)

  // ---- fragment read bases (swizzled)
  const int swp = (lhi ^ ((l15 >> 1) & 3)) * 8;
  const ushort* fA  = &lds[(wm * 64 + l15) * 32 + swp];           // + PB + kk*8192 + (mf>>2)*4096 + (mf&3)*512
  const ushort* fB  = &lds[16384 + (wn * 32 + l15) * 32 + swp];   // + PB + kk*8192 + (nf>>1)*4096 + (nf&1)*512

#define RD_A4(DST, PB, HOFF, KK) \
    _Pragma("unroll") for (int m = 0; m < 4; ++m) \
      DST[m][KK] = *(const bf16x8*)&fA[(PB) + (KK) * 8192 + (HOFF) + m * 512];
#define RD_B4(DST, PB, HOFF) \
    _Pragma("unroll") for (int n = 0; n < 2; ++n) \
    _Pragma("unroll") for (int kk = 0; kk < 2; ++kk) \
      DST[n][kk] = *(const bf16x8*)&fB[(PB) + kk * 8192 + (HOFF) + n * 512];
// kk-outer so kk0 MFMAs issue first (same-phase kk1 reads complete meanwhile)
#define MM4(AR, BV, M0, N0) \
    _Pragma("unroll") for (int kk = 0; kk < 2; ++kk) \
    _Pragma("unroll") for (int m = 0; m < 4; ++m) \
    _Pragma("unroll") for (int n = 0; n < 2; ++n) \
      acc[(M0) + m][(N0) + n] = MFMA_(AR[m][kk], BV[n][kk], acc[(M0) + m][(N0) + n]);
#define BAR   __builtin_amdgcn_s_barrier()
#define PRIO1 __builtin_amdgcn_s_setprio(1)
#define PRIO0 __builtin_amdgcn_s_setprio(0)

  f32x4 acc[8][4] = {};
  bf16x8 a03[4][2], a47[4][2], b23[2][2], b01a[2][2], b01b[2][2];

// one K-tile: reads buf P, prefetches next-tile operands from buf Q in ph4,
// stages tile at k-offset KO into P's regions as they free.
#define KTILE(P, Q, KO, BU, BN) do { \
    RD_A4(a03, P, 0, 1) \
    RD_B4(b23, P, 4096) \
    PRIO1; MM4(a03, BU, 0, 0) PRIO0; BAR; \
    RD_A4(a47, P, 4096, 0) \
    STG(P, 16384, Bb8, vB0, 0, KO); \
    PRIO1; MM4(a03, b23, 0, 2) PRIO0; BAR; \
    RD_A4(a47, P, 4096, 1) \
    STG(P, 0, Ab8, vA0, 0, KO); \
    STG(P, 16384, Bb8, vB1, 1, KO); \
    PRIO1; MM4(a47, b23, 4, 2) PRIO0; \
    asm volatile("s_waitcnt vmcnt(6)" ::: "memory"); \
    BAR; \
    RD_A4(a03, Q, 0, 0) \
    RD_B4(BN, Q, 0) \
    STG(P, 0, Ab8, vA1, 1, KO); \
    PRIO1; MM4(a47, BU, 4, 0) PRIO0; BAR; \
  } while (0)

  // prologue: stage tile0 -> buf0, tile1 -> buf1 (8 GLL each)
  STG(0, 16384, Bb8, vB0, 0, 0);
  STG(0, 0, Ab8, vA0, 0, 0);
  STG(0, 16384, Bb8, vB1, 1, 0);
  STG(0, 0, Ab8, vA1, 1, 0);
  STG(32768, 16384, Bb8, vB0, 0, 64);
  STG(32768, 0, Ab8, vA0, 0, 64);
  STG(32768, 16384, Bb8, vB1, 1, 64);
  STG(32768, 0, Ab8, vA1, 1, 64);
  asm volatile("s_waitcnt vmcnt(8)" ::: "memory");
  BAR;
  // pre-read tile0's ph1 operands (A0 kk0 + B0)
  RD_A4(a03, 0, 0, 0)
  RD_B4(b01a, 0, 0)

#pragma unroll 1
  for (int i = 0; i < 8; ++i) {
    const int t2 = 2 * i + 2, t3 = 2 * i + 3;
    const int ko2 = (t2 < 16 ? t2 : 15) * 64;   // tail: dead re-stage (uniform vmcnt)
    const int ko3 = (t3 < 16 ? t3 : 15) * 64;
    KTILE(0, 32768, ko2, b01a, b01b);
    KTILE(32768, 0, ko3, b01b, b01a);
  }

  asm volatile("s_waitcnt vmcnt(0)" ::: "memory");
  __syncthreads();

  // ---- epilogue ----
  const int rowb = wm * 128;
  if constexpr (MODE == 0) {
    // reuse LDS as [256][64] bf16 x3 (dec/u/gate), XOR-swizzled 8-ushort chunks
    ushort* ldsD = lds;
    ushort* ldsU = lds + 16384;
    ushort* ldsG = lds + 32768;
    const int chl = wn * 16 + l15;           // channel within block's 64
    const int chg = bcol * 64 + chl;         // global channel
    const float ab = abase[chg];
#pragma unroll
    for (int mf = 0; mf < 8; ++mf) {
      const int rl0 = rowb + mf * 16 + lhi * 4;
#pragma unroll
      for (int r = 0; r < 4; ++r) {
        const float zd = acc[mf][0][r];
        const float zs = acc[mf][1][r];
        const float zi = acc[mf][2][r];
        const float zg = acc[mf][3][r];
        float sp = fmaxf(zd, 0.f) + log1pf(__expf(-fabsf(zd)));
        sp = fmaxf(sp, 1e-4f);
        const float dv = __expf(-sp * ab);
        const float sv = 1.f / (1.f + __expf(-zs));
        float tt = __expf(-2.f * fabsf(zi));
        float tv = (1.f - tt) / (1.f + tt);
        tv = (zi < 0.f) ? -tv : tv;
        const float gv = 1.f / (1.f + __expf(-zg));
        const int row = rl0 + r;
        const int idx = row * 64 + ((((chl >> 3) ^ (row & 7)) << 3) | (chl & 7));
        ldsD[idx] = sbf(dv);
        ldsU[idx] = sbf(sv * tv);
        ldsG[idx] = sbf(gv);
      }
    }
    __syncthreads();
    const int srow = t >> 3, cD = t & 7;
    const size_t gbase = (size_t)(brow * 256) * D_ + bcol * 64 + cD * 8;
#pragma unroll
    for (int itp = 0; itp < 4; ++itp) {
      const int row = itp * 64 + srow;
      const int lidx = row * 64 + ((cD ^ (row & 7)) << 3);
      const size_t g = gbase + (size_t)row * D_;
      *(ushort8v*)&dec[g] = *(const ushort8v*)&ldsD[lidx];
      *(ushort8v*)&uu[g]  = *(const ushort8v*)&ldsU[lidx];
      *(ushort8v*)&gat[g] = *(const ushort8v*)&ldsG[lidx];
    }
  } else {
    const int colb = bcol * 256 + wn * 64;
#pragma unroll
    for (int mf = 0; mf < 8; ++mf) {
      const int rl0 = brow * 256 + rowb + mf * 16 + lhi * 4;
#pragma unroll
      for (int nf = 0; nf < 4; ++nf) {
        const int gc = colb + nf * 16 + l15;
#pragma unroll
        for (int r = 0; r < 4; ++r)
          outf[(size_t)(rl0 + r) * 1024 + gc] = acc[mf][nf][r];
      }
    }
  }
#undef KTILE
#undef STG
#undef RD_A4
#undef RD_B4
#undef MM4
}

// ---------------- scan (3-phase chunked, exact affine composition) ----------------
__global__ __launch_bounds__(512) void k_scanA(
    const ushort* __restrict__ dec, const ushort* __restrict__ uu,
    float* __restrict__ cP, float* __restrict__ cL)
{
  const int t  = threadIdx.x;
  const int c  = blockIdx.x & (NCHUNK - 1);
  const int b  = blockIdx.x >> 7;
  const int e2 = t * 2;
  size_t base = ((size_t)b * S_ + (size_t)c * CHLEN) * D_ + e2;
  float P0 = 1.f, P1 = 1.f, L0 = 0.f, L1 = 0.f;
  for (int i = 0; i < CHLEN; ++i) {
    const uint dv = *(const uint*)(dec + base);
    const uint uv = *(const uint*)(uu + base);
    float d0 = bf2f(dv & 0xffffu), d1 = bf2f(dv >> 16);
    P0 *= d0; L0 = fmaf(d0, L0, bf2f(uv & 0xffffu));
    P1 *= d1; L1 = fmaf(d1, L1, bf2f(uv >> 16));
    base += D_;
  }
  size_t o = ((size_t)b * NCHUNK + c) * D_ + e2;
  cP[o] = P0; cP[o + 1] = P1; cL[o] = L0; cL[o + 1] = L1;
}

__global__ __launch_bounds__(64) void k_scanB(
    const float* __restrict__ cP, const float* __restrict__ cL, float* __restrict__ carry)
{
  const int idx = blockIdx.x * 64 + threadIdx.x;  // 0..B_*D_-1
  const int b = idx >> 10, e = idx & 1023;
  float st = 0.f;
  size_t base = (size_t)b * NCHUNK * D_ + e;
  for (int c = 0; c < NCHUNK; ++c) {
    size_t o = base + (size_t)c * D_;
    carry[o] = st;
    st = fmaf(cP[o], st, cL[o]);
  }
}

__global__ __launch_bounds__(512) void k_scanC(
    const ushort* __restrict__ dec, const ushort* __restrict__ uu,
    const ushort* __restrict__ gat, const float* __restrict__ carry,
    ushort* __restrict__ outb)
{
  const int t  = threadIdx.x;
  const int c  = blockIdx.x & (NCHUNK - 1);
  const int b  = blockIdx.x >> 7;
  const int e2 = t * 2;
  size_t co = ((size_t)b * NCHUNK + c) * D_ + e2;
  float s0 = carry[co], s1 = carry[co + 1];
  size_t base = ((size_t)b * S_ + (size_t)c * CHLEN) * D_ + e2;
  for (int i = 0; i < CHLEN; ++i) {
    const uint dv = *(const uint*)(dec + base);
    const uint uv = *(const uint*)(uu + base);
    const uint gv = *(const uint*)(gat + base);
    s0 = fmaf(bf2f(dv & 0xffffu), s0, bf2f(uv & 0xffffu));
    s1 = fmaf(bf2f(dv >> 16),     s1, bf2f(uv >> 16));
    float o0 = bf2f(gv & 0xffffu) * s0;
    float o1 = bf2f(gv >> 16)     * s1;
    *(uint*)(outb + base) = pk2bf(o0, o1);
    base += D_;
  }
}

// ---------------- launcher ----------------
extern "C" void kernel_launch(void* const* d_in, const int* in_sizes, int n_in,
                              void* d_out, int out_size, void* d_ws, size_t ws_size,
                              hipStream_t stream) {
  const float* x     = (const float*)d_in[0];
  const float* W_in  = (const float*)d_in[1];
  const float* W_sel = (const float*)d_in[2];
  const float* W_gat = (const float*)d_in[3];
  const float* W_out = (const float*)d_in[4];
  const float* W_del = (const float*)d_in[5];
  const float* log_a = (const float*)d_in[6];
  float* y = (float*)d_out;

  char* ws = (char*)d_ws;
  size_t off = 0;
  auto alloc = [&](size_t bytes) { char* p = ws + off; off += (bytes + 255) & ~(size_t)255; return p; };
  ushort* xbf   = (ushort*)alloc((size_t)M_ * D_ * 2);   // reused as outb after GEMM0
  ushort* wcat  = (ushort*)alloc((size_t)NCAT * D_ * 2);
  ushort* woutb = (ushort*)alloc((size_t)D_ * D_ * 2);
  ushort* dec   = (ushort*)alloc((size_t)M_ * D_ * 2);
  ushort* uu    = (ushort*)alloc((size_t)M_ * D_ * 2);
  ushort* gat   = (ushort*)alloc((size_t)M_ * D_ * 2);
  float*  cP    = (float*)alloc((size_t)B_ * NCHUNK * D_ * 4);
  float*  cL    = (float*)alloc((size_t)B_ * NCHUNK * D_ * 4);
  float*  carry = (float*)alloc((size_t)B_ * NCHUNK * D_ * 4);
  float*  abase = (float*)alloc(D_ * 4);
  ushort* outb  = xbf;

  // K0: conversions
  k_cvt_f2b4<<<(M_ * D_ / 4 + 255) / 256, 256, 0, stream>>>(x, xbf, M_ * D_ / 4);
  k_build_wcat<<<(NCAT * D_ / 4 + 255) / 256, 256, 0, stream>>>(W_del, W_sel, W_in, W_gat, wcat);
  k_cvt_f2b4<<<(D_ * D_ / 4 + 255) / 256, 256, 0, stream>>>(W_out, woutb, D_ * D_ / 4);
  k_abase<<<(D_ + 255) / 256, 256, 0, stream>>>(log_a, abase);

  // K1: fused 4-projection GEMM + activation epilogue (interleaved Wcat)
  gemm10<0><<<(M_ / 256) * (NCAT / 256), 512, 0, stream>>>(
      xbf, wcat, NCAT / 256, nullptr, dec, uu, gat, abase);

  // K2: chunked scan
  k_scanA<<<B_ * NCHUNK, 512, 0, stream>>>(dec, uu, cP, cL);
  k_scanB<<<(B_ * D_) / 64, 64, 0, stream>>>(cP, cL, carry);
  k_scanC<<<B_ * NCHUNK, 512, 0, stream>>>(dec, uu, gat, carry, outb);

  // K3: output GEMM -> fp32 y
  gemm10<1><<<(M_ / 256) * (D_ / 256), 512, 0, stream>>>(
      outb, woutb, D_ / 256, y, nullptr, nullptr, nullptr, nullptr);
}